// Round 2
// baseline (145.439 us; speedup 1.0000x reference)
//
#include <hip/hip_runtime.h>
#include <math.h>

// N=65536 rows, D=256 fp32. out = sum_i (counts_i - 1)*d_i + exp(d_i)
// d_i = dot(z_a[i], z_b[i]); counts_i-1 = n-3 (i < n-1), n-2 (i == n-1).
//
// R1-R6 all ~44 us: every VGPR-staged load structure (unroll, explicit
// batch arrays, sched_barrier) was collapsed by the allocator to ~1-2
// loads in flight (VGPR_Count 40-52), leaving the kernel latency-bound
// at ~5 B/cyc/CU. R7: global_load_lds width-16 -- global->LDS stream
// with ZERO data VGPRs. 16 instrs/wave (16 KB) issued back-to-back under
// one vmcnt, single s_waitcnt, then an LDS dot-product pass.
// LDS dest must be linear (wave-uniform base + lane*16, no padding), so
// phase 2 breaks bank conflicts with a per-row rotated float4 read.

#define D_DIM 256
#define ROWS_PER_WAVE 8
#define WAVES_PER_BLOCK 4
// blocks = n / (ROWS_PER_WAVE * WAVES_PER_BLOCK) = 65536/32 = 2048

typedef __attribute__((address_space(1))) const unsigned int gu32_t;
typedef __attribute__((address_space(3))) unsigned int su32_t;

__device__ __forceinline__ void gload_lds16(const void* g, void* l) {
    // width=16: one instr moves 64 lanes x 16 B = 1 KB (a full row)
    __builtin_amdgcn_global_load_lds((gu32_t*)g, (su32_t*)l, 16, 0, 0);
}

__global__ __launch_bounds__(256, 2)
void dot_loss_partial(const float4* __restrict__ za4,
                      const float4* __restrict__ zb4,
                      float* __restrict__ partial,
                      int n) {
    // Linear layout (gload_lds requirement): row r of A at A[wave][r][0..255],
    // lane l deposits floats [4l..4l+3]. 64 KB/block -> 2 blocks/CU.
    __shared__ __align__(16) float A[WAVES_PER_BLOCK][ROWS_PER_WAVE][D_DIM];
    __shared__ __align__(16) float B[WAVES_PER_BLOCK][ROWS_PER_WAVE][D_DIM];

    const int lane = threadIdx.x & 63;
    const int wave = threadIdx.x >> 6;
    const int row0 = (blockIdx.x * WAVES_PER_BLOCK + wave) * ROWS_PER_WAVE;

    const float4* a = za4 + (size_t)row0 * 64 + lane;  // per-lane global src
    const float4* b = zb4 + (size_t)row0 * 64 + lane;

    // Phase 1: 16 global_load_lds_dwordx4, no data VGPRs, 16 KB in flight.
    #pragma unroll
    for (int r = 0; r < ROWS_PER_WAVE; ++r) {
        gload_lds16(a + (size_t)r * 64, &A[wave][r][0]);  // LDS base wave-uniform
        gload_lds16(b + (size_t)r * 64, &B[wave][r][0]);
    }
    // Wave-local: only this wave reads its slab -> no barrier, just drain.
    __builtin_amdgcn_s_waitcnt(0);          // vmcnt(0) (+lgkm/exp, free here)
    __builtin_amdgcn_sched_barrier(0);      // keep ds_reads below the wait

    // Phase 2: 8 lanes per row, 8 float4 per lane, per-row rotation so the
    // 8 rows hit 8 distinct 4-bank groups each step (8-touch/bank = the
    // wave64 b128 minimum; ~16 reads * ~12 cyc, negligible).
    const int rowIdx = lane & 7;
    const int cj = lane >> 3;
    const float4* Ar = reinterpret_cast<const float4*>(&A[wave][rowIdx][0]);
    const float4* Br = reinterpret_cast<const float4*>(&B[wave][rowIdx][0]);
    float s = 0.0f;
    #pragma unroll
    for (int c = 0; c < 8; ++c) {
        const int f = cj * 8 + ((c + rowIdx) & 7);
        float4 av = Ar[f];
        float4 bv = Br[f];
        s = fmaf(av.x, bv.x, s);
        s = fmaf(av.y, bv.y, s);
        s = fmaf(av.z, bv.z, s);
        s = fmaf(av.w, bv.w, s);
    }
    // Merge the 8 column-group partials (lanes rowIdx+8k) -> lanes 0..7.
    s += __shfl_down(s, 32);
    s += __shfl_down(s, 16);
    s += __shfl_down(s, 8);

    float acc = 0.0f;
    if (lane < 8) {                          // lane == rowIdx here
        const int row = row0 + lane;
        const float coeff = (row == n - 1) ? (float)(n - 2) : (float)(n - 3);
        acc = coeff * s + expf(s);
    }
    acc += __shfl_down(acc, 4);
    acc += __shfl_down(acc, 2);
    acc += __shfl_down(acc, 1);

    __shared__ float smem[WAVES_PER_BLOCK];
    if (lane == 0) smem[wave] = acc;
    __syncthreads();
    if (threadIdx.x == 0) {
        float s2 = 0.0f;
        #pragma unroll
        for (int w = 0; w < WAVES_PER_BLOCK; ++w) s2 += smem[w];
        partial[blockIdx.x] = s2;
    }
}

__global__ __launch_bounds__(256)
void reduce_partials(const float* __restrict__ partial,
                     float* __restrict__ out,
                     int m) {
    const int lane = threadIdx.x & 63;
    const int wave = threadIdx.x >> 6;
    double s = 0.0;
    for (int i = threadIdx.x; i < m; i += 256)
        s += (double)partial[i];
    #pragma unroll
    for (int off = 32; off > 0; off >>= 1)
        s += __shfl_down(s, off);
    __shared__ double smem[4];
    if (lane == 0) smem[wave] = s;
    __syncthreads();
    if (threadIdx.x == 0)
        out[0] = (float)(smem[0] + smem[1] + smem[2] + smem[3]);
}

extern "C" void kernel_launch(void* const* d_in, const int* in_sizes, int n_in,
                              void* d_out, int out_size, void* d_ws, size_t ws_size,
                              hipStream_t stream) {
    const float4* za4 = (const float4*)d_in[0];
    const float4* zb4 = (const float4*)d_in[1];
    float* out = (float*)d_out;
    float* partial = (float*)d_ws;
    const int n = in_sizes[0] / D_DIM;
    const int blocks = n / (ROWS_PER_WAVE * WAVES_PER_BLOCK);  // 2048

    dot_loss_partial<<<blocks, 256, 0, stream>>>(za4, zb4, partial, n);
    reduce_partials<<<1, 256, 0, stream>>>(partial, out, blocks);
}

// Round 3
// 142.727 us; speedup vs baseline: 1.0190x; 1.0190x over previous
//
#include <hip/hip_runtime.h>
#include <math.h>

// N=65536 rows, D=256 fp32. out = sum_i (counts_i - 1)*d_i + exp(d_i)
// d_i = dot(z_a[i], z_b[i]); counts_i-1 = n-3 (i < n-1), n-2 (i == n-1).
//
// History: R1-R6 VGPR-staged loads all ~44 us (allocator collapsed load
// batches, VGPR 40-52). R7 gload_lds burst-then-drain also ~43 us:
// 2048 short-lived blocks, vmcnt drained to 0 every 16 KB, occupancy 13%
// -> time-averaged in-flight ~4.5 KB/CU. The drain was the limiter.
// R8: persistent pipeline. 512 blocks (exactly 2/CU, resident for the
// whole kernel). Each wave: 32 rows as 8 chunks x (4 rows x 2 arrays
// = 8 KB), double-buffered LDS, issue chunk c+1 then s_waitcnt vmcnt(8)
// (never 0 until tail) -> loads continuously in flight. Chunk compute:
// rotated conflict-free ds_read_b128 dot + 4 shfl + exp on 4 lanes.

#define D_DIM 256
#define ROWS_PER_CHUNK 4
#define CHUNKS_PER_WAVE 8
#define ROWS_PER_WAVE (ROWS_PER_CHUNK * CHUNKS_PER_WAVE)  // 32
#define WAVES_PER_BLOCK 4
// blocks = 65536 / (32*4) = 512 -> 2 blocks/CU, fully resident

typedef __attribute__((address_space(1))) const unsigned int gu32_t;
typedef __attribute__((address_space(3))) unsigned int su32_t;

__device__ __forceinline__ void gload_lds16(const void* g, void* l) {
    // one instr: 64 lanes x 16 B = 1 KB, zero data VGPRs, counted by vmcnt
    __builtin_amdgcn_global_load_lds((gu32_t*)g, (su32_t*)l, 16, 0, 0);
}

__global__ __launch_bounds__(256, 2)
void dot_loss_partial(const float4* __restrict__ za4,
                      const float4* __restrict__ zb4,
                      float* __restrict__ partial,
                      int n) {
    // Linear (unpadded) slabs: gload_lds requires wave-uniform base + lane*16.
    // 2 bufs x 4 rows x 1 KB x 2 arrays x 4 waves = 64 KB/block.
    __shared__ __align__(16) float SA[WAVES_PER_BLOCK][2][ROWS_PER_CHUNK][D_DIM];
    __shared__ __align__(16) float SB[WAVES_PER_BLOCK][2][ROWS_PER_CHUNK][D_DIM];

    const int lane = threadIdx.x & 63;
    const int wave = threadIdx.x >> 6;
    const int row0 = (blockIdx.x * WAVES_PER_BLOCK + wave) * ROWS_PER_WAVE;

    const float4* a = za4 + (size_t)row0 * 64 + lane;  // per-lane global src
    const float4* b = zb4 + (size_t)row0 * 64 + lane;

    const int r_ = lane & 3;    // row within chunk
    const int q_ = lane >> 2;   // column group 0..15 (4 float4 each)

    float acc = 0.0f;

    // Prologue: chunk 0 -> buf 0 (8 loads in flight).
    #pragma unroll
    for (int r = 0; r < ROWS_PER_CHUNK; ++r) {
        gload_lds16(a + (size_t)r * 64, &SA[wave][0][r][0]);
        gload_lds16(b + (size_t)r * 64, &SB[wave][0][r][0]);
    }

    #pragma unroll
    for (int c = 0; c < CHUNKS_PER_WAVE; ++c) {
        const int cur = c & 1;
        if (c + 1 < CHUNKS_PER_WAVE) {
            const int nxt = cur ^ 1;
            #pragma unroll
            for (int r = 0; r < ROWS_PER_CHUNK; ++r) {
                const size_t gr = (size_t)((c + 1) * ROWS_PER_CHUNK + r) * 64;
                gload_lds16(a + gr, &SA[wave][nxt][r][0]);
                gload_lds16(b + gr, &SB[wave][nxt][r][0]);
            }
            // chunk c landed; chunk c+1's 8 loads stay in flight (never 0)
            asm volatile("s_waitcnt vmcnt(8)" ::: "memory");
        } else {
            asm volatile("s_waitcnt vmcnt(0)" ::: "memory");
        }
        __builtin_amdgcn_sched_barrier(0);  // pin ds_reads below the wait

        // Dot of chunk c: lane handles row r_, float4s f = q_*4 + rot.
        // Bank base = (q_&1)*16 + rot*4 -> 8 distinct 4-bank groups, 8 lanes
        // each = the wave64 b128 minimum (conflict-free).
        const float4* Ar = reinterpret_cast<const float4*>(&SA[wave][cur][r_][0]);
        const float4* Br = reinterpret_cast<const float4*>(&SB[wave][cur][r_][0]);
        float s = 0.0f;
        #pragma unroll
        for (int t = 0; t < 4; ++t) {
            const int f = q_ * 4 + ((t + r_) & 3);
            float4 av = Ar[f];
            float4 bv = Br[f];
            s = fmaf(av.x, bv.x, s);
            s = fmaf(av.y, bv.y, s);
            s = fmaf(av.z, bv.z, s);
            s = fmaf(av.w, bv.w, s);
        }
        // Reduce over the 16 column groups (lanes with stride 4 share a row).
        s += __shfl_down(s, 32);
        s += __shfl_down(s, 16);
        s += __shfl_down(s, 8);
        s += __shfl_down(s, 4);
        if (lane < 4) {  // lane == r_ here; s is the full dot d
            const int row = row0 + c * ROWS_PER_CHUNK + lane;
            const float coeff = (row == n - 1) ? (float)(n - 2) : (float)(n - 3);
            acc += coeff * s + expf(s);
        }
    }

    // Merge the 4 per-row accumulators (lanes 0..3) -> lane 0.
    acc += __shfl_down(acc, 2);
    acc += __shfl_down(acc, 1);

    __shared__ float smem[WAVES_PER_BLOCK];
    if (lane == 0) smem[wave] = acc;
    __syncthreads();
    if (threadIdx.x == 0) {
        float s2 = 0.0f;
        #pragma unroll
        for (int w = 0; w < WAVES_PER_BLOCK; ++w) s2 += smem[w];
        partial[blockIdx.x] = s2;
    }
}

__global__ __launch_bounds__(256)
void reduce_partials(const float* __restrict__ partial,
                     float* __restrict__ out,
                     int m) {
    const int lane = threadIdx.x & 63;
    const int wave = threadIdx.x >> 6;
    double s = 0.0;
    for (int i = threadIdx.x; i < m; i += 256)
        s += (double)partial[i];
    #pragma unroll
    for (int off = 32; off > 0; off >>= 1)
        s += __shfl_down(s, off);
    __shared__ double smem[4];
    if (lane == 0) smem[wave] = s;
    __syncthreads();
    if (threadIdx.x == 0)
        out[0] = (float)(smem[0] + smem[1] + smem[2] + smem[3]);
}

extern "C" void kernel_launch(void* const* d_in, const int* in_sizes, int n_in,
                              void* d_out, int out_size, void* d_ws, size_t ws_size,
                              hipStream_t stream) {
    const float4* za4 = (const float4*)d_in[0];
    const float4* zb4 = (const float4*)d_in[1];
    float* out = (float*)d_out;
    float* partial = (float*)d_ws;
    const int n = in_sizes[0] / D_DIM;
    const int blocks = n / (ROWS_PER_WAVE * WAVES_PER_BLOCK);  // 512

    dot_loss_partial<<<blocks, 256, 0, stream>>>(za4, zb4, partial, n);
    reduce_partials<<<1, 256, 0, stream>>>(partial, out, blocks);
}